// Round 2
// baseline (1282.223 us; speedup 1.0000x reference)
//
#include <hip/hip_runtime.h>

#define K_DIM 25088          // n (flattened tokens)
#define R_SCORES 4096        // 4 heads * 1024 memories
#define R_FC 1000
#define BATCH 32

// ---------------------------------------------------------------------------
// Kernel 1: patch embedding + bias + pos_emb -> x5T [25088][32] (transposed)
// grid (32 b, 14 ph), block 256 = 128 e-threads x 2 pw-halves
// ---------------------------------------------------------------------------
__global__ __launch_bounds__(256)
void patch_embed_kernel(const float* __restrict__ x,
                        const float* __restrict__ conv_w,
                        const float* __restrict__ conv_b,
                        const float* __restrict__ pos_emb,
                        float* __restrict__ x5T) {
    const int b  = blockIdx.x;
    const int ph = blockIdx.y;
    const int t  = threadIdx.x;
    const int e    = t & 127;
    const int half = t >> 7;   // 0..1 -> patches pw = half*7 .. +6

    __shared__ __align__(16) float pa[14][768];   // 43 KB: 14 patches of 3*16*16
    __shared__ __align__(16) float ws[32][128];   // 16 KB: conv_w chunk, [k][e]

    // stage 14 patches for this (b, ph)
    for (int idx = t; idx < 14 * 768; idx += 256) {
        int pw = idx / 768;
        int k  = idx % 768;
        int c  = k >> 8;
        int kh = (k >> 4) & 15;
        int kw = k & 15;
        pa[pw][k] = x[((size_t)(b * 3 + c) * 224 + (ph * 16 + kh)) * 224 + pw * 16 + kw];
    }

    float acc[7];
#pragma unroll
    for (int i = 0; i < 7; ++i) acc[i] = 0.f;

    for (int kc = 0; kc < 768; kc += 32) {
        __syncthreads();
        if (t < 128) {
            const float* wr = conv_w + (size_t)t * 768 + kc;
#pragma unroll
            for (int j4 = 0; j4 < 8; ++j4) {
                float4 v = *(const float4*)(wr + j4 * 4);
                ws[j4 * 4 + 0][t] = v.x;
                ws[j4 * 4 + 1][t] = v.y;
                ws[j4 * 4 + 2][t] = v.z;
                ws[j4 * 4 + 3][t] = v.w;
            }
        }
        __syncthreads();
#pragma unroll 1
        for (int j8 = 0; j8 < 32; j8 += 8) {
            float w0 = ws[j8 + 0][e], w1 = ws[j8 + 1][e];
            float w2 = ws[j8 + 2][e], w3 = ws[j8 + 3][e];
            float w4 = ws[j8 + 4][e], w5 = ws[j8 + 5][e];
            float w6 = ws[j8 + 6][e], w7 = ws[j8 + 7][e];
#pragma unroll
            for (int p = 0; p < 7; ++p) {
                const int pw = half * 7 + p;
                float4 a0 = *(const float4*)(&pa[pw][kc + j8]);
                float4 a1 = *(const float4*)(&pa[pw][kc + j8 + 4]);
                float a = acc[p];
                a = fmaf(w0, a0.x, a); a = fmaf(w1, a0.y, a);
                a = fmaf(w2, a0.z, a); a = fmaf(w3, a0.w, a);
                a = fmaf(w4, a1.x, a); a = fmaf(w5, a1.y, a);
                a = fmaf(w6, a1.z, a); a = fmaf(w7, a1.w, a);
                acc[p] = a;
            }
        }
    }

#pragma unroll
    for (int p = 0; p < 7; ++p) {
        const int pw = half * 7 + p;
        const int n  = (ph * 14 + pw) * 128 + e;
        float v = acc[p] + conv_b[e] + pos_emb[n];
        x5T[(size_t)n * 32 + b] = v;
    }
}

// ---------------------------------------------------------------------------
// Skinny GEMM: C[32][R] (+)= xT[K][32]^T * W[R][K]^T, split-K atomic epilogue
// MQUADS=2 -> MC=512 rows/block, MQUADS=1 -> MC=256
// block 256 threads: tm = t&63 (m columns, stride-4 quads), tb = t>>6 (b octet)
// thread tile: MQUADS*4 m  x  8 b = up to 64 accumulators
// grid: (R/MC (ceil), KSPLIT=64)
// ---------------------------------------------------------------------------
template <int MQUADS>
__global__ __launch_bounds__(256)
void skinny_gemm_kernel(const float* __restrict__ xT,   // [K_DIM][32]
                        const float* __restrict__ W,    // [R][K_DIM]
                        const float* __restrict__ bias, // [R] or nullptr
                        float* __restrict__ C,          // [32][R]
                        int R) {
    constexpr int MC = 256 * MQUADS;
    constexpr int KSPLIT = 64;
    constexpr int KB = K_DIM / KSPLIT;  // 392
    constexpr int KC = 8;               // 49 phases
    const int m0  = blockIdx.x * MC;
    const int kb0 = blockIdx.y * KB;
    const int t  = threadIdx.x;
    const int tm = t & 63;
    const int tb = t >> 6;              // b-octet: b = tb*8 + j

    __shared__ __align__(16) float Xs[KC][MC];
    __shared__ __align__(16) float x5s[KC][32];

    float acc[MQUADS][4][8];
#pragma unroll
    for (int q = 0; q < MQUADS; ++q)
#pragma unroll
        for (int i = 0; i < 4; ++i)
#pragma unroll
            for (int j = 0; j < 8; ++j) acc[q][i][j] = 0.f;

    for (int phse = 0; phse < KB / KC; ++phse) {
        const int kpos = kb0 + phse * KC;
        __syncthreads();
        // stage W rows: MC rows, 8 floats each
#pragma unroll
        for (int rr = 0; rr < MQUADS; ++rr) {
            int r = t + rr * 256;
            int row = m0 + r;
            float4 v0 = make_float4(0.f, 0.f, 0.f, 0.f);
            float4 v1 = v0;
            if (row < R) {
                const float* wp = W + (size_t)row * K_DIM + kpos;
                v0 = *(const float4*)(wp);
                v1 = *(const float4*)(wp + 4);
            }
            Xs[0][r] = v0.x; Xs[1][r] = v0.y; Xs[2][r] = v0.z; Xs[3][r] = v0.w;
            Xs[4][r] = v1.x; Xs[5][r] = v1.y; Xs[6][r] = v1.z; Xs[7][r] = v1.w;
        }
        // stage x5 chunk: KC*32 = 256 floats, contiguous
        if (t < 64) {
            float4 v = *(const float4*)(xT + (size_t)kpos * 32 + t * 4);
            ((float4*)(&x5s[0][0]))[t] = v;
        }
        __syncthreads();
#pragma unroll
        for (int kk = 0; kk < KC; ++kk) {
            const float4 xa = *(const float4*)(&x5s[kk][tb * 8]);
            const float4 xb = *(const float4*)(&x5s[kk][tb * 8 + 4]);
            float xj[8] = {xa.x, xa.y, xa.z, xa.w, xb.x, xb.y, xb.z, xb.w};
#pragma unroll
            for (int q = 0; q < MQUADS; ++q) {
                const float4 wv = *(const float4*)(&Xs[kk][q * 256 + tm * 4]);
                float wi[4] = {wv.x, wv.y, wv.z, wv.w};
#pragma unroll
                for (int i = 0; i < 4; ++i)
#pragma unroll
                    for (int j = 0; j < 8; ++j)
                        acc[q][i][j] = fmaf(wi[i], xj[j], acc[q][i][j]);
            }
        }
    }

    const bool add_bias = (bias != nullptr) && (blockIdx.y == 0);
#pragma unroll
    for (int q = 0; q < MQUADS; ++q) {
#pragma unroll
        for (int i = 0; i < 4; ++i) {
            const int row = m0 + q * 256 + tm * 4 + i;
            if (row < R) {
                const float bv = add_bias ? bias[row] : 0.f;
#pragma unroll
                for (int j = 0; j < 8; ++j) {
                    atomicAdd(&C[(size_t)(tb * 8 + j) * R + row], acc[q][i][j] + bv);
                }
            }
        }
    }
}

// ---------------------------------------------------------------------------
// Softmax over 1024 memories per (b,h); writes probsT[h][m][b] scaled by 0.25
// grid (32, 4), block 256
// ---------------------------------------------------------------------------
__global__ __launch_bounds__(256)
void softmax_kernel(const float* __restrict__ scores,  // [32][4096]
                    float* __restrict__ probsT) {      // [4][1024][32]
    const int b = blockIdx.x;
    const int h = blockIdx.y;
    const int t = threadIdx.x;
    const float* row = scores + (size_t)b * 4096 + h * 1024;
    float4 v = *(const float4*)(row + t * 4);

    __shared__ float red[256];
    float lm = fmaxf(fmaxf(v.x, v.y), fmaxf(v.z, v.w));
    red[t] = lm;
    __syncthreads();
    for (int s = 128; s > 0; s >>= 1) {
        if (t < s) red[t] = fmaxf(red[t], red[t + s]);
        __syncthreads();
    }
    const float M = red[0];
    __syncthreads();

    float e0 = expf(v.x - M);
    float e1 = expf(v.y - M);
    float e2 = expf(v.z - M);
    float e3 = expf(v.w - M);
    red[t] = e0 + e1 + e2 + e3;
    __syncthreads();
    for (int s = 128; s > 0; s >>= 1) {
        if (t < s) red[t] += red[t + s];
        __syncthreads();
    }
    const float inv = 0.25f / red[0];

    const int m = t * 4;
    probsT[((size_t)h * 1024 + m + 0) * 32 + b] = e0 * inv;
    probsT[((size_t)h * 1024 + m + 1) * 32 + b] = e1 * inv;
    probsT[((size_t)h * 1024 + m + 2) * 32 + b] = e2 * inv;
    probsT[((size_t)h * 1024 + m + 3) * 32 + b] = e3 * inv;
}

// ---------------------------------------------------------------------------
// Retrieval: x7T[n][b] (+)= sum_m probsT[h][m][b] * X[h][m][n]  (0.25 folded in)
// grid (196 n-chunks, 4 h, 2 m-halves), block 256: col = t&31 (4 n), brow = t>>5 (4 b)
// ---------------------------------------------------------------------------
__global__ __launch_bounds__(256)
void retrieval_kernel(const float* __restrict__ probsT, // [4][1024][32]
                      const float* __restrict__ X,      // [4][1024][25088]
                      float* __restrict__ x7T) {        // [25088][32]
    const int n0 = blockIdx.x * 128;
    const int h  = blockIdx.y;
    const int m0 = blockIdx.z * 512;
    const int t  = threadIdx.x;
    const int col  = t & 31;
    const int brow = t >> 5;       // 0..7  -> b0 = brow*4
    const int n = n0 + col * 4;

    float acc[4][4];
#pragma unroll
    for (int i = 0; i < 4; ++i)
#pragma unroll
        for (int j = 0; j < 4; ++j) acc[i][j] = 0.f;

    const float* Xp = X + (size_t)(h * 1024 + m0) * K_DIM + n;
    const float* pp = probsT + (size_t)(h * 1024 + m0) * 32 + brow * 4;

#pragma unroll 4
    for (int m = 0; m < 512; ++m) {
        float4 xv = *(const float4*)Xp;
        float4 pv = *(const float4*)pp;
        float xi[4] = {xv.x, xv.y, xv.z, xv.w};
        float pj[4] = {pv.x, pv.y, pv.z, pv.w};
#pragma unroll
        for (int i = 0; i < 4; ++i)
#pragma unroll
            for (int j = 0; j < 4; ++j)
                acc[i][j] = fmaf(xi[i], pj[j], acc[i][j]);
        Xp += K_DIM;
        pp += 32;
    }

#pragma unroll
    for (int i = 0; i < 4; ++i)
#pragma unroll
        for (int j = 0; j < 4; ++j)
            atomicAdd(&x7T[(size_t)(n + i) * 32 + brow * 4 + j], acc[i][j]);
}

// ---------------------------------------------------------------------------
extern "C" void kernel_launch(void* const* d_in, const int* in_sizes, int n_in,
                              void* d_out, int out_size, void* d_ws, size_t ws_size,
                              hipStream_t stream) {
    const float* x      = (const float*)d_in[0];
    const float* conv_w = (const float*)d_in[1];
    const float* conv_b = (const float*)d_in[2];
    const float* pos    = (const float*)d_in[3];
    const float* hopX   = (const float*)d_in[4];
    const float* fc_w   = (const float*)d_in[5];
    const float* fc_b   = (const float*)d_in[6];
    float* out = (float*)d_out;

    char* ws = (char*)d_ws;
    const size_t X5T_BYTES    = (size_t)K_DIM * 32 * 4;   // 3,211,264
    const size_t SCORES_BYTES = (size_t)32 * 4096 * 4;    //   524,288
    const size_t PROBS_BYTES  = (size_t)4 * 1024 * 32 * 4;//   524,288
    float* x5T    = (float*)(ws);
    float* scores = (float*)(ws + X5T_BYTES);
    float* probsT = (float*)(ws + X5T_BYTES + SCORES_BYTES);
    float* x7T    = (float*)(ws + X5T_BYTES + SCORES_BYTES + PROBS_BYTES);

    hipMemsetAsync(scores, 0, SCORES_BYTES, stream);
    hipMemsetAsync(x7T, 0, X5T_BYTES, stream);
    hipMemsetAsync(out, 0, (size_t)32 * R_FC * 4, stream);

    // 1. patch embed -> x5T
    patch_embed_kernel<<<dim3(32, 14), 256, 0, stream>>>(x, conv_w, conv_b, pos, x5T);
    // 2. scores[b][h*1024+m] = x5 . hop_X  (split-K atomics)
    skinny_gemm_kernel<2><<<dim3(8, 64), 256, 0, stream>>>(x5T, hopX, nullptr, scores, R_SCORES);
    // 3. softmax -> probsT (pre-scaled by 1/heads)
    softmax_kernel<<<dim3(32, 4), 256, 0, stream>>>(scores, probsT);
    // 4. retrieval + head mean -> x7T
    retrieval_kernel<<<dim3(196, 4, 2), 256, 0, stream>>>(probsT, hopX, x7T);
    // 5. FC: out = x7 . fc_w^T + fc_b
    skinny_gemm_kernel<1><<<dim3(4, 64), 256, 0, stream>>>(x7T, fc_w, fc_b, out, R_FC);
}